// Round 2
// baseline (427.074 us; speedup 1.0000x reference)
//
#include <hip/hip_runtime.h>

typedef __bf16 bf16;
typedef __bf16 bf16x8 __attribute__((ext_vector_type(8)));
typedef float  f32x4  __attribute__((ext_vector_type(4)));

#define T_TOTAL 9792
#define EMBED   1024
#define NHEAD   16
#define HDIM    64

// Fixed problem geometry (LENGTHS are compile-time constants of this problem).
__constant__ int c_seq_start[12] = {0,1024,1792,2688,3200,4224,4864,5888,6656,7168,8064,9088};
__constant__ int c_tiles_cum[13] = {0,16,28,42,50,66,76,92,104,112,126,142,153};

typedef __attribute__((address_space(1))) unsigned int gu32;
typedef __attribute__((address_space(3))) unsigned int lu32;

// async global->LDS, 16B per lane. LDS dest is wave-uniform base + lane*16.
__device__ __forceinline__ void load_lds16(const void* g, void* l) {
    __builtin_amdgcn_global_load_lds((gu32*)g, (lu32*)l, 16, 0, 0);
}

__device__ __forceinline__ f32x4 mfma16(bf16x8 a, bf16x8 b, f32x4 c) {
    return __builtin_amdgcn_mfma_f32_16x16x32_bf16(a, b, c, 0, 0, 0);
}

// ---------------------------------------------------------------------------
// Dtype canonicalization. Discriminator: cos[0][0]==1.0 exactly (pos 0).
// fp32 storage -> first uint16 is 0x0000; bf16 storage -> 0x3F80.
// ---------------------------------------------------------------------------
__global__ void to_bf16(const void* __restrict__ src, bf16* __restrict__ dst, int n,
                        const unsigned short* __restrict__ disc)
{
    const bool f32 = (disc[0] == 0);
    int i = (blockIdx.x * blockDim.x + threadIdx.x) * 8;
    if (i >= n) return;
    bf16x8 o;
    if (f32) {
        const float4* s = (const float4*)((const float*)src + i);
        float4 a = s[0], b = s[1];
        o[0]=(bf16)a.x; o[1]=(bf16)a.y; o[2]=(bf16)a.z; o[3]=(bf16)a.w;
        o[4]=(bf16)b.x; o[5]=(bf16)b.y; o[6]=(bf16)b.z; o[7]=(bf16)b.w;
    } else {
        o = *(const bf16x8*)((const bf16*)src + i);
    }
    *(bf16x8*)(dst + i) = o;
}

__global__ void store_out(const bf16* __restrict__ src, void* __restrict__ dst, int n,
                          const unsigned short* __restrict__ disc)
{
    const bool f32 = (disc[0] == 0);
    int i = (blockIdx.x * blockDim.x + threadIdx.x) * 8;
    if (i >= n) return;
    bf16x8 v = *(const bf16x8*)(src + i);
    if (f32) {
        float4 a, b;
        a.x=(float)v[0]; a.y=(float)v[1]; a.z=(float)v[2]; a.w=(float)v[3];
        b.x=(float)v[4]; b.y=(float)v[5]; b.z=(float)v[6]; b.w=(float)v[7];
        float4* d = (float4*)((float*)dst + i);
        d[0] = a; d[1] = b;
    } else {
        *(bf16x8*)((bf16*)dst + i) = v;
    }
}

// ---------------------------------------------------------------------------
// C[M x 1024] = A[M x 1024] @ W[1024 x 1024]^T + bias   (all bf16, fp32 acc)
// m97 recipe: 128x128 tile, BK=64, 4 waves (2x2), global_load_lds staging.
// ---------------------------------------------------------------------------
__global__ __launch_bounds__(256, 2)
void gemm_bt(const bf16* __restrict__ A, const bf16* __restrict__ W,
             const bf16* __restrict__ bias, bf16* __restrict__ C, int M)
{
    __shared__ __align__(16) bf16 lA[128 * 64];
    __shared__ __align__(16) bf16 lB[128 * 64];

    const int tid  = threadIdx.x;
    const int wave = tid >> 6, lane = tid & 63;
    const int lrow = lane >> 3, lcol = (lane & 7) * 8;   // staging: 8 lanes/row
    const int ln   = lane & 15, lq   = lane >> 4;        // mfma lane coords
    const int m0 = blockIdx.x * 128, n0 = blockIdx.y * 128;
    const int wm = (wave & 1) * 64,  wn = (wave >> 1) * 64;

    f32x4 acc[4][4] = {};

    for (int k0 = 0; k0 < 1024; k0 += 64) {
        __syncthreads();
        for (int j = 0; j < 4; ++j) {
            int r = j * 32 + wave * 8;                    // wave-uniform row base
            int gr = m0 + r + lrow; if (gr > M - 1) gr = M - 1;
            load_lds16(A + (size_t)gr * EMBED + k0 + lcol, &lA[r * 64]);
            load_lds16(W + (size_t)(n0 + r + lrow) * EMBED + k0 + lcol, &lB[r * 64]);
        }
        __syncthreads();
        for (int kk = 0; kk < 64; kk += 32) {
            bf16x8 af[4], bfr[4];
            for (int i = 0; i < 4; ++i)
                af[i]  = *(const bf16x8*)&lA[(wm + i * 16 + ln) * 64 + kk + lq * 8];
            for (int i = 0; i < 4; ++i)
                bfr[i] = *(const bf16x8*)&lB[(wn + i * 16 + ln) * 64 + kk + lq * 8];
            for (int mi = 0; mi < 4; ++mi)
                for (int ni = 0; ni < 4; ++ni)
                    acc[mi][ni] = mfma16(af[mi], bfr[ni], acc[mi][ni]);
        }
    }

    // C/D layout (verified m89/m91): col = lane&15, row = (lane>>4)*4 + r
    for (int mi = 0; mi < 4; ++mi) {
        int row = m0 + wm + mi * 16 + lq * 4;
        for (int ni = 0; ni < 4; ++ni) {
            int col = n0 + wn + ni * 16 + ln;
            float bv = bias ? (float)bias[col] : 0.0f;
            for (int r = 0; r < 4; ++r) {
                int rr = row + r;
                if (rr < M) C[(size_t)rr * EMBED + col] = (bf16)(acc[mi][ni][r] + bv);
            }
        }
    }
}

// ---------------------------------------------------------------------------
// RoPE in place on Q and K (blockIdx.y selects tensor). 8 dims per thread.
// cos[t][d] == cos[t][d+32] (freqs duplicated), same for sin.
// ---------------------------------------------------------------------------
__global__ void rope_kernel(bf16* Q, bf16* K,
                            const bf16* __restrict__ cosb, const bf16* __restrict__ sinb)
{
    int idx = blockIdx.x * blockDim.x + threadIdx.x;   // T*16*4 threads per tensor
    bf16* P = blockIdx.y ? K : Q;
    int t = idx >> 6;
    int rem = idx & 63;
    int h = rem >> 2;
    int d0 = (rem & 3) * 8;                            // within [0,32)
    size_t base = (size_t)t * EMBED + h * HDIM + d0;
    bf16x8 x0 = *(bf16x8*)&P[base];
    bf16x8 x1 = *(bf16x8*)&P[base + 32];
    bf16x8 cv = *(const bf16x8*)&cosb[t * HDIM + d0];
    bf16x8 sv = *(const bf16x8*)&sinb[t * HDIM + d0];
    bf16x8 y0, y1;
    for (int i = 0; i < 8; ++i) {
        float a = (float)x0[i], b = (float)x1[i];
        float c = (float)cv[i], s = (float)sv[i];
        y0[i] = (bf16)(a * c - b * s);
        y1[i] = (bf16)(b * c + a * s);
    }
    *(bf16x8*)&P[base]      = y0;
    *(bf16x8*)&P[base + 32] = y1;
}

// ---------------------------------------------------------------------------
// V (T x 1024, head-interleaved) -> Vt (per head: HDIM x T) so PV B-fragments
// are 16B-contiguous. XOR-swizzled LDS tile (granule = (d/8)^(t&7)).
// ---------------------------------------------------------------------------
__global__ __launch_bounds__(256, 2)
void transpose_v(const bf16* __restrict__ V, bf16* __restrict__ Vt)
{
    __shared__ __align__(16) bf16 tile[64 * 64];
    const int tt = blockIdx.x, h = blockIdx.y;
    const int tid = threadIdx.x;
    const int t0 = tt * 64;
    for (int p = 0; p < 2; ++p) {
        int tl = (tid >> 3) + p * 32;
        int d0 = (tid & 7) * 8;
        bf16x8 v = *(const bf16x8*)&V[(size_t)(t0 + tl) * EMBED + h * HDIM + d0];
        int g = (d0 >> 3) ^ (tl & 7);
        *(bf16x8*)&tile[tl * 64 + g * 8] = v;
    }
    __syncthreads();
    for (int p = 0; p < 2; ++p) {
        int d  = (tid >> 3) + p * 32;
        int t8 = (tid & 7) * 8;
        int rot = (tid >> 3) & 7;                       // spread banks on reads
        bf16x8 vals;
        for (int i = 0; i < 8; ++i) {
            int ii = (i + rot) & 7;
            int tl = t8 + ii;
            int g  = (d >> 3) ^ ii;
            vals[ii] = tile[tl * 64 + g * 8 + (d & 7)];
        }
        *(bf16x8*)&Vt[(size_t)(h * HDIM + d) * T_TOTAL + t0 + t8] = vals;
    }
}

// ---------------------------------------------------------------------------
// Flash attention: block = (64-row q-tile, head), 4 waves x 16 q-rows each.
// All lengths/starts are multiples of 64 -> tiles always full; only the
// diagonal kv-tile needs per-element causal masking. exp2 domain softmax.
// O is written into the Q buffer (exact same region the block read).
// ---------------------------------------------------------------------------
__global__ __launch_bounds__(256, 2)
void attn_kernel(const bf16* Q, const bf16* __restrict__ K,
                 const bf16* __restrict__ Vt, bf16* O)
{
    __shared__ __align__(16) bf16 sQ[64 * 64];
    __shared__ __align__(16) bf16 sK[64 * 64];
    __shared__ __align__(16) bf16 sV[64 * 64];       // Vt tile: [dh][kv]
    __shared__ __align__(16) bf16 sP[4][16 * 72];    // per-wave, pad 72 (4-way max)

    const int tid  = threadIdx.x;
    const int wave = tid >> 6, lane = tid & 63;
    const int lrow = lane >> 3, lcol = (lane & 7) * 8;
    const int ln   = lane & 15, lq   = lane >> 4;
    const int h = blockIdx.y;

    int b = 0;
    #pragma unroll
    for (int i = 1; i < 13; ++i) if ((int)blockIdx.x >= c_tiles_cum[i]) b = i;
    const int qt = blockIdx.x - c_tiles_cum[b];
    const int t0 = c_seq_start[b] + qt * 64;

    for (int p = 0; p < 2; ++p) {
        int r = p * 32 + wave * 8;
        load_lds16(Q + (size_t)(t0 + r + lrow) * EMBED + h * HDIM + lcol, &sQ[r * 64]);
    }
    __syncthreads();
    bf16x8 qf[2];
    qf[0] = *(const bf16x8*)&sQ[(wave * 16 + ln) * 64 + 0  + lq * 8];
    qf[1] = *(const bf16x8*)&sQ[(wave * 16 + ln) * 64 + 32 + lq * 8];

    f32x4 oacc[4] = {};
    float m_i[4], l_i[4];
    for (int r = 0; r < 4; ++r) { m_i[r] = -1e30f; l_i[r] = 0.f; }
    const float sc = 0.125f * 1.44269504088896f;     // 1/sqrt(64) * log2(e)
    const int q_local = wave * 16 + lq * 4;          // + r

    for (int j = 0; j <= qt; ++j) {
        __syncthreads();
        const int kvb = c_seq_start[b] + j * 64;
        for (int p = 0; p < 2; ++p) {
            int r = p * 32 + wave * 8;
            load_lds16(K  + (size_t)(kvb + r + lrow) * EMBED + h * HDIM + lcol, &sK[r * 64]);
            load_lds16(Vt + (size_t)(h * HDIM + r + lrow) * T_TOTAL + kvb + lcol, &sV[r * 64]);
        }
        __syncthreads();

        f32x4 s[4] = {};
        for (int kk = 0; kk < 2; ++kk)
            for (int ni = 0; ni < 4; ++ni) {
                bf16x8 kf = *(const bf16x8*)&sK[(ni * 16 + ln) * 64 + kk * 32 + lq * 8];
                s[ni] = mfma16(qf[kk], kf, s[ni]);
            }

        float pb[4][4];
        for (int ni = 0; ni < 4; ++ni)
            for (int r = 0; r < 4; ++r) {
                float v = s[ni][r] * sc;
                if (j == qt && (ni * 16 + ln) > (q_local + r)) v = -1e30f;
                pb[ni][r] = v;
            }

        float mnew[4], alpha[4];
        for (int r = 0; r < 4; ++r) {
            float mx = fmaxf(fmaxf(pb[0][r], pb[1][r]), fmaxf(pb[2][r], pb[3][r]));
            mx = fmaxf(mx, __shfl_xor(mx, 1));
            mx = fmaxf(mx, __shfl_xor(mx, 2));
            mx = fmaxf(mx, __shfl_xor(mx, 4));
            mx = fmaxf(mx, __shfl_xor(mx, 8));
            mnew[r]  = fmaxf(m_i[r], mx);
            alpha[r] = exp2f(m_i[r] - mnew[r]);
            m_i[r]   = mnew[r];
        }
        float rs[4] = {0.f, 0.f, 0.f, 0.f};
        for (int ni = 0; ni < 4; ++ni)
            for (int r = 0; r < 4; ++r) {
                float p = exp2f(pb[ni][r] - mnew[r]);
                pb[ni][r] = p;
                rs[r] += p;
            }
        for (int r = 0; r < 4; ++r) {
            rs[r] += __shfl_xor(rs[r], 1);
            rs[r] += __shfl_xor(rs[r], 2);
            rs[r] += __shfl_xor(rs[r], 4);
            rs[r] += __shfl_xor(rs[r], 8);
            l_i[r] = l_i[r] * alpha[r] + rs[r];
        }
        for (int d = 0; d < 4; ++d)
            for (int r = 0; r < 4; ++r)
                oacc[d][r] *= alpha[r];

        // P: C-layout -> A-layout via per-wave LDS (m120-verified transform)
        for (int ni = 0; ni < 4; ++ni)
            for (int r = 0; r < 4; ++r)
                sP[wave][(lq * 4 + r) * 72 + ni * 16 + ln] = (bf16)pb[ni][r];
        asm volatile("s_waitcnt lgkmcnt(0)" ::: "memory");   // per-wave sP visibility

        for (int kk = 0; kk < 2; ++kk) {
            bf16x8 pf = *(const bf16x8*)&sP[wave][ln * 72 + kk * 32 + lq * 8];
            for (int d = 0; d < 4; ++d) {
                bf16x8 vf = *(const bf16x8*)&sV[(d * 16 + ln) * 64 + kk * 32 + lq * 8];
                oacc[d] = mfma16(pf, vf, oacc[d]);
            }
        }
    }

    for (int r = 0; r < 4; ++r) l_i[r] = 1.0f / l_i[r];
    for (int d = 0; d < 4; ++d)
        for (int r = 0; r < 4; ++r) {
            size_t row = (size_t)t0 + wave * 16 + lq * 4 + r;
            O[row * EMBED + h * HDIM + d * 16 + ln] = (bf16)(oacc[d][r] * l_i[r]);
        }
}

// ---------------------------------------------------------------------------
extern "C" void kernel_launch(void* const* d_in, const int* in_sizes, int n_in,
                              void* d_out, int out_size, void* d_ws, size_t ws_size,
                              hipStream_t stream)
{
    const unsigned short* disc = (const unsigned short*)d_in[1];  // cos[0][0]

    const size_t SZ  = (size_t)T_TOTAL * EMBED;   // 10,027,008
    const size_t CS  = (size_t)T_TOTAL * HDIM;    // 626,688
    const size_t WSZ = (size_t)EMBED * EMBED;     // 1,048,576

    bf16* p = (bf16*)d_ws;
    bf16* ch   = p; p += SZ;
    bf16* ccos = p; p += CS;
    bf16* csin = p; p += CS;
    bf16* cqw  = p; p += WSZ;
    bf16* ckw  = p; p += WSZ;
    bf16* cvw  = p; p += WSZ;
    bf16* cow  = p; p += WSZ;
    bf16* cqb  = p; p += EMBED;
    bf16* cvb  = p; p += EMBED;
    bf16* cob  = p; p += EMBED;
    bf16* wq   = p; p += SZ;      // Q (post-RoPE), then attention output (in place)
    bf16* wk   = p; p += SZ;
    bf16* wv   = p; p += SZ;      // V, later reused for out-proj bf16 result
    bf16* wvt  = p; p += SZ;      // total ~106 MB

    auto cvt = [&](const void* src, bf16* dst, int n) {
        int blocks = (n / 8 + 255) / 256;
        to_bf16<<<blocks, 256, 0, stream>>>(src, dst, n, disc);
    };
    cvt(d_in[0], ch,   (int)SZ);
    cvt(d_in[1], ccos, (int)CS);
    cvt(d_in[2], csin, (int)CS);
    cvt(d_in[3], cqw,  (int)WSZ);
    cvt(d_in[4], cqb,  EMBED);
    cvt(d_in[5], ckw,  (int)WSZ);
    cvt(d_in[6], cvw,  (int)WSZ);
    cvt(d_in[7], cvb,  EMBED);
    cvt(d_in[8], cow,  (int)WSZ);
    cvt(d_in[9], cob,  EMBED);

    dim3 gg(77, 8);
    gemm_bt<<<gg, 256, 0, stream>>>(ch, cqw, cqb,     wq, T_TOTAL);
    gemm_bt<<<gg, 256, 0, stream>>>(ch, ckw, nullptr, wk, T_TOTAL);
    gemm_bt<<<gg, 256, 0, stream>>>(ch, cvw, cvb,     wv, T_TOTAL);
    rope_kernel<<<dim3(2448, 2), 256, 0, stream>>>(wq, wk, ccos, csin);
    transpose_v<<<dim3(153, 16), 256, 0, stream>>>(wv, wvt);
    attn_kernel<<<dim3(153, 16), 256, 0, stream>>>(wq, wk, wvt, wq);
    gemm_bt<<<gg, 256, 0, stream>>>(wq, cow, cob, wv, T_TOTAL);
    store_out<<<(int)((SZ / 8 + 255) / 256), 256, 0, stream>>>(wv, d_out, (int)SZ, disc);
}

// Round 3
// 355.771 us; speedup vs baseline: 1.2004x; 1.2004x over previous
//
#include <hip/hip_runtime.h>

typedef __bf16 bf16;
typedef __bf16 bf16x8 __attribute__((ext_vector_type(8)));
typedef __bf16 bf16x4 __attribute__((ext_vector_type(4)));
typedef float  f32x4  __attribute__((ext_vector_type(4)));

#define T_TOTAL 9792
#define EMBED   1024
#define NHEAD   16
#define HDIM    64

// Fixed problem geometry (LENGTHS are compile-time constants of this problem).
__constant__ int c_seq_start[12] = {0,1024,1792,2688,3200,4224,4864,5888,6656,7168,8064,9088};
__constant__ int c_tiles_cum[13] = {0,16,28,42,50,66,76,92,104,112,126,142,153};

typedef __attribute__((address_space(1))) unsigned int gu32;
typedef __attribute__((address_space(3))) unsigned int lu32;

// async global->LDS, 16B per lane. LDS dest is wave-uniform base + lane*16.
__device__ __forceinline__ void load_lds16(const void* g, void* l) {
    __builtin_amdgcn_global_load_lds((gu32*)g, (lu32*)l, 16, 0, 0);
}

__device__ __forceinline__ f32x4 mfma16(bf16x8 a, bf16x8 b, f32x4 c) {
    return __builtin_amdgcn_mfma_f32_16x16x32_bf16(a, b, c, 0, 0, 0);
}

// ---------------------------------------------------------------------------
// Dtype canonicalization. Discriminator: cos[0][0]==1.0 exactly (pos 0).
// fp32 storage -> first uint16 is 0x0000; bf16 storage -> 0x3F80.
// ---------------------------------------------------------------------------
__global__ void to_bf16(const void* __restrict__ src, bf16* __restrict__ dst, int n,
                        const unsigned short* __restrict__ disc)
{
    const bool f32 = (disc[0] == 0);
    int i = (blockIdx.x * blockDim.x + threadIdx.x) * 8;
    if (i >= n) return;
    bf16x8 o;
    if (f32) {
        const float4* s = (const float4*)((const float*)src + i);
        float4 a = s[0], b = s[1];
        o[0]=(bf16)a.x; o[1]=(bf16)a.y; o[2]=(bf16)a.z; o[3]=(bf16)a.w;
        o[4]=(bf16)b.x; o[5]=(bf16)b.y; o[6]=(bf16)b.z; o[7]=(bf16)b.w;
    } else {
        o = *(const bf16x8*)((const bf16*)src + i);
    }
    *(bf16x8*)(dst + i) = o;
}

__global__ void store_out(const bf16* __restrict__ src, void* __restrict__ dst, int n,
                          const unsigned short* __restrict__ disc)
{
    const bool f32 = (disc[0] == 0);
    int i = (blockIdx.x * blockDim.x + threadIdx.x) * 8;
    if (i >= n) return;
    bf16x8 v = *(const bf16x8*)(src + i);
    if (f32) {
        float4 a, b;
        a.x=(float)v[0]; a.y=(float)v[1]; a.z=(float)v[2]; a.w=(float)v[3];
        b.x=(float)v[4]; b.y=(float)v[5]; b.z=(float)v[6]; b.w=(float)v[7];
        float4* d = (float4*)((float*)dst + i);
        d[0] = a; d[1] = b;
    } else {
        *(bf16x8*)((bf16*)dst + i) = v;
    }
}

// ---------------------------------------------------------------------------
// GEMM body: C[128 tile] = A @ W^T + bias. XOR-swizzled LDS (granule ^ row&7)
// applied on the GLOBAL side of staging so global_load_lds stays contiguous;
// b128 fragment reads become bank-conflict-free.
// ---------------------------------------------------------------------------
__device__ __forceinline__
void gemm_body(const bf16* __restrict__ A, const bf16* __restrict__ W,
               const bf16* __restrict__ bias, bf16* __restrict__ C,
               int M, int m0, int n0)
{
    __shared__ __align__(16) bf16 lA[128 * 64];
    __shared__ __align__(16) bf16 lB[128 * 64];

    const int tid  = threadIdx.x;
    const int wave = tid >> 6, lane = tid & 63;
    const int lrow = lane >> 3;
    const int gsw  = (lane & 7) ^ lrow;                  // swizzled granule
    const int ln   = lane & 15, lq = lane >> 4;
    const int e7   = ln & 7;
    const int wm = (wave & 1) * 64,  wn = (wave >> 1) * 64;

    f32x4 acc[4][4] = {};

    for (int k0 = 0; k0 < 1024; k0 += 64) {
        __syncthreads();
        for (int j = 0; j < 4; ++j) {
            int r = j * 32 + wave * 8;                    // wave-uniform row base
            int gr = m0 + r + lrow; if (gr > M - 1) gr = M - 1;
            load_lds16(A + (size_t)gr * EMBED + k0 + gsw * 8, &lA[r * 64]);
            load_lds16(W + (size_t)(n0 + r + lrow) * EMBED + k0 + gsw * 8, &lB[r * 64]);
        }
        __syncthreads();
        #pragma unroll
        for (int kb = 0; kb < 2; ++kb) {
            bf16x8 af[4], bfr[4];
            #pragma unroll
            for (int i = 0; i < 4; ++i)
                af[i]  = *(const bf16x8*)&lA[(wm + i * 16 + ln) * 64 + (((kb * 4 + lq) ^ e7) * 8)];
            #pragma unroll
            for (int i = 0; i < 4; ++i)
                bfr[i] = *(const bf16x8*)&lB[(wn + i * 16 + ln) * 64 + (((kb * 4 + lq) ^ e7) * 8)];
            #pragma unroll
            for (int mi = 0; mi < 4; ++mi)
                #pragma unroll
                for (int ni = 0; ni < 4; ++ni)
                    acc[mi][ni] = mfma16(af[mi], bfr[ni], acc[mi][ni]);
        }
    }

    // C/D layout (verified m89/m91): col = lane&15, row = (lane>>4)*4 + r
    for (int mi = 0; mi < 4; ++mi) {
        int row = m0 + wm + mi * 16 + lq * 4;
        for (int ni = 0; ni < 4; ++ni) {
            int col = n0 + wn + ni * 16 + ln;
            float bv = bias ? (float)bias[col] : 0.0f;
            for (int r = 0; r < 4; ++r) {
                int rr = row + r;
                if (rr < M) C[(size_t)rr * EMBED + col] = (bf16)(acc[mi][ni][r] + bv);
            }
        }
    }
}

__global__ __launch_bounds__(256, 2)
void gemm_bt(const bf16* __restrict__ A, const bf16* __restrict__ W,
             const bf16* __restrict__ bias, bf16* __restrict__ C, int M)
{
    gemm_body(A, W, bias, C, M, blockIdx.x * 128, blockIdx.y * 128);
}

// QKV fused: blockIdx.y in [0,24): y>>3 selects {Q,K,V}, y&7 selects n-tile.
__global__ __launch_bounds__(256, 2)
void gemm_qkv(const bf16* __restrict__ A,
              const bf16* __restrict__ Wq, const bf16* __restrict__ Wk,
              const bf16* __restrict__ Wv, const bf16* __restrict__ qb,
              const bf16* __restrict__ vb,
              bf16* __restrict__ Cq, bf16* __restrict__ Ck, bf16* __restrict__ Cv, int M)
{
    const int which = blockIdx.y >> 3;
    const bf16* W    = (which == 0) ? Wq : (which == 1) ? Wk : Wv;
    const bf16* bias = (which == 0) ? qb : (which == 1) ? nullptr : vb;
    bf16* C          = (which == 0) ? Cq : (which == 1) ? Ck : Cv;
    gemm_body(A, W, bias, C, M, blockIdx.x * 128, (blockIdx.y & 7) * 128);
}

// ---------------------------------------------------------------------------
// RoPE in place on Q and K (blockIdx.y selects tensor). 8 dims per thread.
// ---------------------------------------------------------------------------
__global__ void rope_kernel(bf16* Q, bf16* K,
                            const bf16* __restrict__ cosb, const bf16* __restrict__ sinb)
{
    int idx = blockIdx.x * blockDim.x + threadIdx.x;
    bf16* P = blockIdx.y ? K : Q;
    int t = idx >> 6;
    int rem = idx & 63;
    int h = rem >> 2;
    int d0 = (rem & 3) * 8;
    size_t base = (size_t)t * EMBED + h * HDIM + d0;
    bf16x8 x0 = *(bf16x8*)&P[base];
    bf16x8 x1 = *(bf16x8*)&P[base + 32];
    bf16x8 cv = *(const bf16x8*)&cosb[t * HDIM + d0];
    bf16x8 sv = *(const bf16x8*)&sinb[t * HDIM + d0];
    bf16x8 y0, y1;
    for (int i = 0; i < 8; ++i) {
        float a = (float)x0[i], b = (float)x1[i];
        float c = (float)cv[i], s = (float)sv[i];
        y0[i] = (bf16)(a * c - b * s);
        y1[i] = (bf16)(b * c + a * s);
    }
    *(bf16x8*)&P[base]      = y0;
    *(bf16x8*)&P[base + 32] = y1;
}

// ---------------------------------------------------------------------------
// V (T x 1024, head-interleaved) -> Vt (per head: HDIM x T).
// ---------------------------------------------------------------------------
__global__ __launch_bounds__(256, 2)
void transpose_v(const bf16* __restrict__ V, bf16* __restrict__ Vt)
{
    __shared__ __align__(16) bf16 tile[64 * 64];
    const int tt = blockIdx.x, h = blockIdx.y;
    const int tid = threadIdx.x;
    const int t0 = tt * 64;
    for (int p = 0; p < 2; ++p) {
        int tl = (tid >> 3) + p * 32;
        int d0 = (tid & 7) * 8;
        bf16x8 v = *(const bf16x8*)&V[(size_t)(t0 + tl) * EMBED + h * HDIM + d0];
        int g = (d0 >> 3) ^ (tl & 7);
        *(bf16x8*)&tile[tl * 64 + g * 8] = v;
    }
    __syncthreads();
    for (int p = 0; p < 2; ++p) {
        int d  = (tid >> 3) + p * 32;
        int t8 = (tid & 7) * 8;
        int rot = (tid >> 3) & 7;
        bf16x8 vals;
        for (int i = 0; i < 8; ++i) {
            int ii = (i + rot) & 7;
            int tl = t8 + ii;
            int g  = (d >> 3) ^ ii;
            vals[ii] = tile[tl * 64 + g * 8 + (d & 7)];
        }
        *(bf16x8*)&Vt[(size_t)(h * HDIM + d) * T_TOTAL + t0 + t8] = vals;
    }
}

// ---------------------------------------------------------------------------
// Flash attention, S^T formulation.
//   S^T = mfma(kf, qf): C col = q (=ln), row = kv (=16ni+4lq+r)
//     -> each lane holds 16 scores of ONE q-row: softmax = in-lane + 2 shfl.
//   O^T = mfma(vf, pf): Vt tile as A [dh][kv], P rows [q][kv] as B.
// sQ/sK/sV rows XOR-swizzled (granule ^ row&7) via global-side permutation
// so staging stays contiguous and b128 reads are conflict-free.
// Single barrier per j-iter; next K/V tile prefetched before compute.
// ---------------------------------------------------------------------------
__global__ __launch_bounds__(256, 3)
void attn_kernel(const bf16* __restrict__ Q, const bf16* __restrict__ K,
                 const bf16* __restrict__ Vt, bf16* __restrict__ O)
{
    __shared__ __align__(16) bf16 sK[2][64 * 64];
    __shared__ __align__(16) bf16 sV[2][64 * 64];       // Vt tile: [dh][kv]
    __shared__ __align__(16) bf16 sQP[4 * 16 * 72];     // Q tile (first 8KB), later per-wave P

    const int tid  = threadIdx.x;
    const int wave = tid >> 6, lane = tid & 63;
    const int lrow = lane >> 3;
    const int gsw  = (lane & 7) ^ lrow;                  // staging granule swizzle
    const int ln   = lane & 15, lq = lane >> 4;
    const int e7   = ln & 7;
    const int h = blockIdx.y;

    int b = 0;
    #pragma unroll
    for (int i = 1; i < 13; ++i) if ((int)blockIdx.x >= c_tiles_cum[i]) b = i;
    const int qt = blockIdx.x - c_tiles_cum[b];
    const int t0 = c_seq_start[b] + qt * 64;
    const int kvb0 = c_seq_start[b];

    // prologue: stage Q (into sQP) and K/V tile 0
    for (int p = 0; p < 2; ++p) {
        int r = p * 32 + wave * 8;
        load_lds16(Q  + (size_t)(t0 + r + lrow) * EMBED + h * HDIM + gsw * 8, &sQP[r * 64]);
        load_lds16(K  + (size_t)(kvb0 + r + lrow) * EMBED + h * HDIM + gsw * 8, &sK[0][r * 64]);
        load_lds16(Vt + (size_t)(h * HDIM + r + lrow) * T_TOTAL + kvb0 + gsw * 8, &sV[0][r * 64]);
    }

    bf16x8 qf[2];
    f32x4 oacc[4] = {};
    float m_i = -1e30f, l_i = 0.0f;
    const float sc = 0.125f * 1.44269504088896f;        // 1/sqrt(64) * log2(e)
    const int q_loc = wave * 16 + ln;                   // q within 64-tile
    bf16* sP = &sQP[wave * 16 * 72];                    // per-wave P rows [q16][72]

    for (int j = 0; j <= qt; ++j) {
        __syncthreads();
        const int cur = j & 1;
        if (j == 0) {
            qf[0] = *(const bf16x8*)&sQP[q_loc * 64 + ((0 + lq) ^ e7) * 8];
            qf[1] = *(const bf16x8*)&sQP[q_loc * 64 + ((4 + lq) ^ e7) * 8];
            __syncthreads();                            // sQP becomes sP after this
        }
        if (j < qt) {                                   // prefetch next K/V tile
            const int kvb = kvb0 + (j + 1) * 64;
            const int nxt = cur ^ 1;
            for (int p = 0; p < 2; ++p) {
                int r = p * 32 + wave * 8;
                load_lds16(K  + (size_t)(kvb + r + lrow) * EMBED + h * HDIM + gsw * 8, &sK[nxt][r * 64]);
                load_lds16(Vt + (size_t)(h * HDIM + r + lrow) * T_TOTAL + kvb + gsw * 8, &sV[nxt][r * 64]);
            }
        }

        f32x4 s[4] = {};
        #pragma unroll
        for (int kk = 0; kk < 2; ++kk)
            #pragma unroll
            for (int ni = 0; ni < 4; ++ni) {
                bf16x8 kf = *(const bf16x8*)&sK[cur][(ni * 16 + ln) * 64 + (((kk * 4 + lq) ^ e7) * 8)];
                s[ni] = mfma16(kf, qf[kk], s[ni]);      // S^T[kv][q]
            }

        float pb[4][4];
        if (j == qt) {
            #pragma unroll
            for (int ni = 0; ni < 4; ++ni)
                #pragma unroll
                for (int r = 0; r < 4; ++r) {
                    int kv = ni * 16 + lq * 4 + r;
                    pb[ni][r] = (kv <= q_loc) ? s[ni][r] * sc : -1e30f;
                }
        } else {
            #pragma unroll
            for (int ni = 0; ni < 4; ++ni)
                #pragma unroll
                for (int r = 0; r < 4; ++r)
                    pb[ni][r] = s[ni][r] * sc;
        }

        float mx = pb[0][0];
        #pragma unroll
        for (int ni = 0; ni < 4; ++ni)
            #pragma unroll
            for (int r = 0; r < 4; ++r) mx = fmaxf(mx, pb[ni][r]);
        mx = fmaxf(mx, __shfl_xor(mx, 16));
        mx = fmaxf(mx, __shfl_xor(mx, 32));
        float mnew  = fmaxf(m_i, mx);
        float alpha = exp2f(m_i - mnew);
        m_i = mnew;

        float rs = 0.0f;
        #pragma unroll
        for (int ni = 0; ni < 4; ++ni)
            #pragma unroll
            for (int r = 0; r < 4; ++r) {
                float pe = exp2f(pb[ni][r] - mnew);
                pb[ni][r] = pe;
                rs += pe;
            }
        rs += __shfl_xor(rs, 16);
        rs += __shfl_xor(rs, 32);
        l_i = l_i * alpha + rs;
        #pragma unroll
        for (int d = 0; d < 4; ++d)
            #pragma unroll
            for (int r = 0; r < 4; ++r) oacc[d][r] *= alpha;

        // P rows [q=ln][kv]: lane writes kv = 16ni+4lq..+3 as one 8B store (2-way free)
        #pragma unroll
        for (int ni = 0; ni < 4; ++ni) {
            bf16x4 w4;
            #pragma unroll
            for (int r = 0; r < 4; ++r) w4[r] = (bf16)pb[ni][r];
            *(bf16x4*)&sP[ln * 72 + ni * 16 + lq * 4] = w4;
        }
        asm volatile("s_waitcnt lgkmcnt(0)" ::: "memory");  // same-wave sP visibility

        #pragma unroll
        for (int kk = 0; kk < 2; ++kk) {
            bf16x8 pf = *(const bf16x8*)&sP[ln * 72 + kk * 32 + lq * 8];
            #pragma unroll
            for (int d = 0; d < 4; ++d) {
                bf16x8 vf = *(const bf16x8*)&sV[cur][(d * 16 + ln) * 64 + (((kk * 4 + lq) ^ e7) * 8)];
                oacc[d] = mfma16(vf, pf, oacc[d]);      // O^T[dh][q]
            }
        }
    }

    // O^T C-layout: col=ln=q, row=lq*4+r=dh (within d-tile). 8B packed stores.
    const float inv = 1.0f / l_i;
    const size_t row = (size_t)(t0 + q_loc) * EMBED + h * HDIM;
    #pragma unroll
    for (int d = 0; d < 4; ++d) {
        bf16x4 o4;
        #pragma unroll
        for (int r = 0; r < 4; ++r) o4[r] = (bf16)(oacc[d][r] * inv);
        *(bf16x4*)&O[row + d * 16 + lq * 4] = o4;
    }
}

// ---------------------------------------------------------------------------
extern "C" void kernel_launch(void* const* d_in, const int* in_sizes, int n_in,
                              void* d_out, int out_size, void* d_ws, size_t ws_size,
                              hipStream_t stream)
{
    const unsigned short* disc = (const unsigned short*)d_in[1];  // cos[0][0]

    const size_t SZ  = (size_t)T_TOTAL * EMBED;   // 10,027,008
    const size_t CS  = (size_t)T_TOTAL * HDIM;    // 626,688
    const size_t WSZ = (size_t)EMBED * EMBED;     // 1,048,576

    bf16* p = (bf16*)d_ws;
    bf16* ch   = p; p += SZ;
    bf16* ccos = p; p += CS;
    bf16* csin = p; p += CS;
    bf16* cqw  = p; p += WSZ;
    bf16* ckw  = p; p += WSZ;
    bf16* cvw  = p; p += WSZ;
    bf16* cow  = p; p += WSZ;
    bf16* cqb  = p; p += EMBED;
    bf16* cvb  = p; p += EMBED;
    bf16* cob  = p; p += EMBED;
    bf16* wq   = p; p += SZ;      // Q (post-RoPE), then attention output (in place)
    bf16* wk   = p; p += SZ;
    bf16* wv   = p; p += SZ;      // V, later reused for out-proj bf16 result
    bf16* wvt  = p; p += SZ;

    auto cvt = [&](const void* src, bf16* dst, int n) {
        int blocks = (n / 8 + 255) / 256;
        to_bf16<<<blocks, 256, 0, stream>>>(src, dst, n, disc);
    };
    cvt(d_in[0], ch,   (int)SZ);
    cvt(d_in[1], ccos, (int)CS);
    cvt(d_in[2], csin, (int)CS);
    cvt(d_in[3], cqw,  (int)WSZ);
    cvt(d_in[4], cqb,  EMBED);
    cvt(d_in[5], ckw,  (int)WSZ);
    cvt(d_in[6], cvw,  (int)WSZ);
    cvt(d_in[7], cvb,  EMBED);
    cvt(d_in[8], cow,  (int)WSZ);
    cvt(d_in[9], cob,  EMBED);

    gemm_qkv<<<dim3(77, 24), 256, 0, stream>>>(ch, cqw, ckw, cvw, cqb, cvb,
                                               wq, wk, wv, T_TOTAL);
    rope_kernel<<<dim3(2448, 2), 256, 0, stream>>>(wq, wk, ccos, csin);
    transpose_v<<<dim3(153, 16), 256, 0, stream>>>(wv, wvt);
    attn_kernel<<<dim3(153, 16), 256, 0, stream>>>(wq, wk, wvt, wq);
    gemm_bt<<<dim3(77, 8), 256, 0, stream>>>(wq, cow, cob, wv, T_TOTAL);
    store_out<<<(int)((SZ / 8 + 255) / 256), 256, 0, stream>>>(wv, d_out, (int)SZ, disc);
}

// Round 4
// 283.479 us; speedup vs baseline: 1.5065x; 1.2550x over previous
//
#include <hip/hip_runtime.h>

typedef __bf16 bf16;
typedef __bf16 bf16x8 __attribute__((ext_vector_type(8)));
typedef __bf16 bf16x4 __attribute__((ext_vector_type(4)));
typedef float  f32x4  __attribute__((ext_vector_type(4)));

#define T_TOTAL 9792
#define EMBED   1024
#define NHEAD   16
#define HDIM    64

// Fixed problem geometry (LENGTHS are compile-time constants of this problem).
__constant__ int c_seq_start[12] = {0,1024,1792,2688,3200,4224,4864,5888,6656,7168,8064,9088};
__constant__ int c_tiles_cum[13] = {0,16,28,42,50,66,76,92,104,112,126,142,153};

typedef __attribute__((address_space(1))) unsigned int gu32;
typedef __attribute__((address_space(3))) unsigned int lu32;

__device__ __forceinline__ void load_lds16(const void* g, void* l) {
    __builtin_amdgcn_global_load_lds((gu32*)g, (lu32*)l, 16, 0, 0);
}

__device__ __forceinline__ f32x4 mfma16(bf16x8 a, bf16x8 b, f32x4 c) {
    return __builtin_amdgcn_mfma_f32_16x16x32_bf16(a, b, c, 0, 0, 0);
}

// ---------------------------------------------------------------------------
// Fused dtype canonicalization: all 10 tensors in one dispatch.
// Discriminator: cos[0][0]==1.0 exactly -> fp32 first u16 is 0x0000.
// ---------------------------------------------------------------------------
struct CvtArgs {
    const void* src[10];
    bf16*       dst[10];
    int         n[10];
    int         cum[10];   // block offset of each segment
};

__global__ void to_bf16_fused(CvtArgs a, const unsigned short* __restrict__ disc)
{
    const bool f32 = (disc[0] == 0);
    const int blk = blockIdx.x;
    int seg = 0;
    #pragma unroll
    for (int i = 1; i < 10; ++i) if (blk >= a.cum[i]) seg = i;
    int i0 = (blk - a.cum[seg]) * 2048 + threadIdx.x * 8;
    if (i0 >= a.n[seg]) return;
    bf16x8 o;
    if (f32) {
        const float4* s = (const float4*)((const float*)a.src[seg] + i0);
        float4 x = s[0], y = s[1];
        o[0]=(bf16)x.x; o[1]=(bf16)x.y; o[2]=(bf16)x.z; o[3]=(bf16)x.w;
        o[4]=(bf16)y.x; o[5]=(bf16)y.y; o[6]=(bf16)y.z; o[7]=(bf16)y.w;
    } else {
        o = *(const bf16x8*)((const bf16*)a.src[seg] + i0);
    }
    *(bf16x8*)(a.dst[seg] + i0) = o;
}

// ---------------------------------------------------------------------------
// Shared GEMM core: acc = A[m0:+128] @ W[n0:+128]^T  (K=1024, BK=64).
// XOR-swizzled LDS (granule ^ row&7) applied on the GLOBAL side of staging;
// b128 fragment reads bank-conflict-free (verified: 0 conflicts in R3).
// ---------------------------------------------------------------------------
__device__ __forceinline__
void gemm_core(const bf16* __restrict__ A, const bf16* __restrict__ W,
               int M, int m0, int n0, f32x4 (&acc)[4][4],
               bf16* lA, bf16* lB)
{
    const int tid  = threadIdx.x;
    const int wave = tid >> 6, lane = tid & 63;
    const int lrow = lane >> 3;
    const int gsw  = (lane & 7) ^ lrow;
    const int ln   = lane & 15, lq = lane >> 4;
    const int e7   = ln & 7;
    const int wm = (wave & 1) * 64,  wn = (wave >> 1) * 64;

    for (int k0 = 0; k0 < 1024; k0 += 64) {
        __syncthreads();
        for (int j = 0; j < 4; ++j) {
            int r = j * 32 + wave * 8;
            int gr = m0 + r + lrow; if (gr > M - 1) gr = M - 1;
            load_lds16(A + (size_t)gr * EMBED + k0 + gsw * 8, &lA[r * 64]);
            load_lds16(W + (size_t)(n0 + r + lrow) * EMBED + k0 + gsw * 8, &lB[r * 64]);
        }
        __syncthreads();
        #pragma unroll
        for (int kb = 0; kb < 2; ++kb) {
            bf16x8 af[4], bfr[4];
            #pragma unroll
            for (int i = 0; i < 4; ++i)
                af[i]  = *(const bf16x8*)&lA[(wm + i * 16 + ln) * 64 + (((kb * 4 + lq) ^ e7) * 8)];
            #pragma unroll
            for (int i = 0; i < 4; ++i)
                bfr[i] = *(const bf16x8*)&lB[(wn + i * 16 + ln) * 64 + (((kb * 4 + lq) ^ e7) * 8)];
            #pragma unroll
            for (int mi = 0; mi < 4; ++mi)
                #pragma unroll
                for (int ni = 0; ni < 4; ++ni)
                    acc[mi][ni] = mfma16(af[mi], bfr[ni], acc[mi][ni]);
        }
    }
}

// Supertile block map: 8 x-tiles per super-column x all NY, L2/L3 locality.
__device__ __forceinline__ void map_block(int L, int NY, int& x, int& y)
{
    const int per = 8 * NY;
    const int full = 9 * per;          // 72 of 77 x-tiles in full supercols
    if (L < full) { int sc = L / per, rem = L % per; x = sc * 8 + (rem & 7); y = rem >> 3; }
    else          { int rem = L - full; x = 72 + rem % 5; y = rem / 5; }
}

// ---------------------------------------------------------------------------
// QKV fused GEMM. 1D grid 77*24. which = y>>3 selects {Q,K,V}.
// Epilogue fuses: bias add, RoPE (Q,K; on fp32 acc), V transpose -> Vt.
// ---------------------------------------------------------------------------
__global__ __launch_bounds__(256, 2)
void gemm_qkv(const bf16* __restrict__ A,
              const bf16* __restrict__ Wq, const bf16* __restrict__ Wk,
              const bf16* __restrict__ Wv, const bf16* __restrict__ qb,
              const bf16* __restrict__ vb,
              const bf16* __restrict__ cosb, const bf16* __restrict__ sinb,
              bf16* __restrict__ Cq, bf16* __restrict__ Ck,
              bf16* __restrict__ Vt, int M)
{
    __shared__ __align__(16) bf16 lA[128 * 64];
    __shared__ __align__(16) bf16 lB[128 * 64];

    int x, yy;
    map_block(blockIdx.x, 24, x, yy);
    const int which = yy >> 3;
    const int m0 = x * 128, n0 = (yy & 7) * 128;

    const bf16* W = (which == 0) ? Wq : (which == 1) ? Wk : Wv;
    f32x4 acc[4][4] = {};
    gemm_core(A, W, M, m0, n0, acc, lA, lB);

    const int tid  = threadIdx.x;
    const int wave = tid >> 6, lane = tid & 63;
    const int ln   = lane & 15, lq = lane >> 4;
    const int wm = (wave & 1) * 64,  wn = (wave >> 1) * 64;

    if (which < 2) {
        // Q or K: bias (Q only) + RoPE on fp32 acc. Pair (d, d+32) = (ni, ni+2).
        bf16* C = (which == 0) ? Cq : Ck;
        const bf16* bias = (which == 0) ? qb : nullptr;
        #pragma unroll
        for (int mi = 0; mi < 4; ++mi) {
            int trow = m0 + wm + mi * 16 + lq * 4;
            if (trow >= M) continue;
            #pragma unroll
            for (int ni = 0; ni < 2; ++ni) {
                int d    = ni * 16 + ln;           // in [0,32)
                int col0 = n0 + wn + d;
                int col1 = col0 + 32;
                float b0 = bias ? (float)bias[col0] : 0.0f;
                float b1 = bias ? (float)bias[col1] : 0.0f;
                #pragma unroll
                for (int r = 0; r < 4; ++r) {
                    int t = trow + r;
                    float c = (float)cosb[t * HDIM + d];
                    float s = (float)sinb[t * HDIM + d];
                    float x0 = acc[mi][ni][r] + b0;
                    float x1 = acc[mi][ni + 2][r] + b1;
                    C[(size_t)t * EMBED + col0] = (bf16)(x0 * c - x1 * s);
                    C[(size_t)t * EMBED + col1] = (bf16)(x1 * c + x0 * s);
                }
            }
        }
    } else {
        // V: bias + direct transposed store Vt[(h*64+d) * T + t] (8B per (mi,ni))
        const int hd0 = n0 + wn;                    // multiple of 64
        #pragma unroll
        for (int mi = 0; mi < 4; ++mi) {
            int trow = m0 + wm + mi * 16 + lq * 4;
            if (trow >= M) continue;
            #pragma unroll
            for (int ni = 0; ni < 4; ++ni) {
                int d = ni * 16 + ln;
                float bv = (float)vb[hd0 + d];
                bf16x4 o;
                #pragma unroll
                for (int r = 0; r < 4; ++r) o[r] = (bf16)(acc[mi][ni][r] + bv);
                *(bf16x4*)&Vt[(size_t)(hd0 + d) * T_TOTAL + trow] = o;
            }
        }
    }
}

// ---------------------------------------------------------------------------
// Out-proj GEMM: writes d_out directly (fp32 or bf16 per disc).
// ---------------------------------------------------------------------------
__global__ __launch_bounds__(256, 2)
void gemm_out(const bf16* __restrict__ A, const bf16* __restrict__ W,
              const bf16* __restrict__ bias, void* __restrict__ out, int M,
              const unsigned short* __restrict__ disc)
{
    __shared__ __align__(16) bf16 lA[128 * 64];
    __shared__ __align__(16) bf16 lB[128 * 64];

    int x, yy;
    map_block(blockIdx.x, 8, x, yy);
    const int m0 = x * 128, n0 = yy * 128;

    f32x4 acc[4][4] = {};
    gemm_core(A, W, M, m0, n0, acc, lA, lB);

    const bool f32 = (disc[0] == 0);
    const int tid  = threadIdx.x;
    const int wave = tid >> 6, lane = tid & 63;
    const int ln   = lane & 15, lq = lane >> 4;
    const int wm = (wave & 1) * 64,  wn = (wave >> 1) * 64;

    #pragma unroll
    for (int mi = 0; mi < 4; ++mi) {
        int trow = m0 + wm + mi * 16 + lq * 4;
        if (trow >= M) continue;
        #pragma unroll
        for (int ni = 0; ni < 4; ++ni) {
            int col = n0 + wn + ni * 16 + ln;
            float bv = (float)bias[col];
            #pragma unroll
            for (int r = 0; r < 4; ++r) {
                float v = acc[mi][ni][r] + bv;
                size_t idx = (size_t)(trow + r) * EMBED + col;
                if (f32) ((float*)out)[idx] = v;
                else     ((bf16*)out)[idx]  = (bf16)v;
            }
        }
    }
}

// ---------------------------------------------------------------------------
// Flash attention, S^T formulation (unchanged from R3 — verified).
// ---------------------------------------------------------------------------
__global__ __launch_bounds__(256, 3)
void attn_kernel(const bf16* __restrict__ Q, const bf16* __restrict__ K,
                 const bf16* __restrict__ Vt, bf16* __restrict__ O)
{
    __shared__ __align__(16) bf16 sK[2][64 * 64];
    __shared__ __align__(16) bf16 sV[2][64 * 64];       // Vt tile: [dh][kv]
    __shared__ __align__(16) bf16 sQP[4 * 16 * 72];     // Q tile, later per-wave P

    const int tid  = threadIdx.x;
    const int wave = tid >> 6, lane = tid & 63;
    const int lrow = lane >> 3;
    const int gsw  = (lane & 7) ^ lrow;
    const int ln   = lane & 15, lq = lane >> 4;
    const int e7   = ln & 7;
    const int h = blockIdx.y;

    int b = 0;
    #pragma unroll
    for (int i = 1; i < 13; ++i) if ((int)blockIdx.x >= c_tiles_cum[i]) b = i;
    const int qt = blockIdx.x - c_tiles_cum[b];
    const int t0 = c_seq_start[b] + qt * 64;
    const int kvb0 = c_seq_start[b];

    for (int p = 0; p < 2; ++p) {
        int r = p * 32 + wave * 8;
        load_lds16(Q  + (size_t)(t0 + r + lrow) * EMBED + h * HDIM + gsw * 8, &sQP[r * 64]);
        load_lds16(K  + (size_t)(kvb0 + r + lrow) * EMBED + h * HDIM + gsw * 8, &sK[0][r * 64]);
        load_lds16(Vt + (size_t)(h * HDIM + r + lrow) * T_TOTAL + kvb0 + gsw * 8, &sV[0][r * 64]);
    }

    bf16x8 qf[2];
    f32x4 oacc[4] = {};
    float m_i = -1e30f, l_i = 0.0f;
    const float sc = 0.125f * 1.44269504088896f;
    const int q_loc = wave * 16 + ln;
    bf16* sP = &sQP[wave * 16 * 72];

    for (int j = 0; j <= qt; ++j) {
        __syncthreads();
        const int cur = j & 1;
        if (j == 0) {
            qf[0] = *(const bf16x8*)&sQP[q_loc * 64 + ((0 + lq) ^ e7) * 8];
            qf[1] = *(const bf16x8*)&sQP[q_loc * 64 + ((4 + lq) ^ e7) * 8];
            __syncthreads();
        }
        if (j < qt) {
            const int kvb = kvb0 + (j + 1) * 64;
            const int nxt = cur ^ 1;
            for (int p = 0; p < 2; ++p) {
                int r = p * 32 + wave * 8;
                load_lds16(K  + (size_t)(kvb + r + lrow) * EMBED + h * HDIM + gsw * 8, &sK[nxt][r * 64]);
                load_lds16(Vt + (size_t)(h * HDIM + r + lrow) * T_TOTAL + kvb + gsw * 8, &sV[nxt][r * 64]);
            }
        }

        f32x4 s[4] = {};
        #pragma unroll
        for (int kk = 0; kk < 2; ++kk)
            #pragma unroll
            for (int ni = 0; ni < 4; ++ni) {
                bf16x8 kf = *(const bf16x8*)&sK[cur][(ni * 16 + ln) * 64 + (((kk * 4 + lq) ^ e7) * 8)];
                s[ni] = mfma16(kf, qf[kk], s[ni]);      // S^T[kv][q]
            }

        float pb[4][4];
        if (j == qt) {
            #pragma unroll
            for (int ni = 0; ni < 4; ++ni)
                #pragma unroll
                for (int r = 0; r < 4; ++r) {
                    int kv = ni * 16 + lq * 4 + r;
                    pb[ni][r] = (kv <= q_loc) ? s[ni][r] * sc : -1e30f;
                }
        } else {
            #pragma unroll
            for (int ni = 0; ni < 4; ++ni)
                #pragma unroll
                for (int r = 0; r < 4; ++r)
                    pb[ni][r] = s[ni][r] * sc;
        }

        float mx = pb[0][0];
        #pragma unroll
        for (int ni = 0; ni < 4; ++ni)
            #pragma unroll
            for (int r = 0; r < 4; ++r) mx = fmaxf(mx, pb[ni][r]);
        mx = fmaxf(mx, __shfl_xor(mx, 16));
        mx = fmaxf(mx, __shfl_xor(mx, 32));
        float mnew  = fmaxf(m_i, mx);
        float alpha = exp2f(m_i - mnew);
        m_i = mnew;

        float rs = 0.0f;
        #pragma unroll
        for (int ni = 0; ni < 4; ++ni)
            #pragma unroll
            for (int r = 0; r < 4; ++r) {
                float pe = exp2f(pb[ni][r] - mnew);
                pb[ni][r] = pe;
                rs += pe;
            }
        rs += __shfl_xor(rs, 16);
        rs += __shfl_xor(rs, 32);
        l_i = l_i * alpha + rs;
        #pragma unroll
        for (int d = 0; d < 4; ++d)
            #pragma unroll
            for (int r = 0; r < 4; ++r) oacc[d][r] *= alpha;

        #pragma unroll
        for (int ni = 0; ni < 4; ++ni) {
            bf16x4 w4;
            #pragma unroll
            for (int r = 0; r < 4; ++r) w4[r] = (bf16)pb[ni][r];
            *(bf16x4*)&sP[ln * 72 + ni * 16 + lq * 4] = w4;
        }
        asm volatile("s_waitcnt lgkmcnt(0)" ::: "memory");

        #pragma unroll
        for (int kk = 0; kk < 2; ++kk) {
            bf16x8 pf = *(const bf16x8*)&sP[ln * 72 + kk * 32 + lq * 8];
            #pragma unroll
            for (int d = 0; d < 4; ++d) {
                bf16x8 vf = *(const bf16x8*)&sV[cur][(d * 16 + ln) * 64 + (((kk * 4 + lq) ^ e7) * 8)];
                oacc[d] = mfma16(vf, pf, oacc[d]);      // O^T[dh][q]
            }
        }
    }

    const float inv = 1.0f / l_i;
    const size_t row = (size_t)(t0 + q_loc) * EMBED + h * HDIM;
    #pragma unroll
    for (int d = 0; d < 4; ++d) {
        bf16x4 o4;
        #pragma unroll
        for (int r = 0; r < 4; ++r) o4[r] = (bf16)(oacc[d][r] * inv);
        *(bf16x4*)&O[row + d * 16 + lq * 4] = o4;
    }
}

// ---------------------------------------------------------------------------
extern "C" void kernel_launch(void* const* d_in, const int* in_sizes, int n_in,
                              void* d_out, int out_size, void* d_ws, size_t ws_size,
                              hipStream_t stream)
{
    const unsigned short* disc = (const unsigned short*)d_in[1];  // cos[0][0]

    const size_t SZ  = (size_t)T_TOTAL * EMBED;   // 10,027,008
    const size_t CS  = (size_t)T_TOTAL * HDIM;    // 626,688
    const size_t WSZ = (size_t)EMBED * EMBED;     // 1,048,576

    bf16* p = (bf16*)d_ws;
    bf16* ch   = p; p += SZ;
    bf16* ccos = p; p += CS;
    bf16* csin = p; p += CS;
    bf16* cqw  = p; p += WSZ;
    bf16* ckw  = p; p += WSZ;
    bf16* cvw  = p; p += WSZ;
    bf16* cow  = p; p += WSZ;
    bf16* cqb  = p; p += EMBED;
    bf16* cvb  = p; p += EMBED;
    bf16* cob  = p; p += EMBED;
    bf16* wq   = p; p += SZ;      // Q (post-RoPE), then attention output (in place)
    bf16* wk   = p; p += SZ;
    bf16* wvt  = p; p += SZ;      // V^T per head

    CvtArgs ca;
    const void* srcs[10] = {d_in[0], d_in[1], d_in[2], d_in[3], d_in[5],
                            d_in[6], d_in[8], d_in[4], d_in[7], d_in[9]};
    bf16* dsts[10] = {ch, ccos, csin, cqw, ckw, cvw, cow, cqb, cvb, cob};
    int   ns[10]   = {(int)SZ, (int)CS, (int)CS, (int)WSZ, (int)WSZ,
                      (int)WSZ, (int)WSZ, EMBED, EMBED, EMBED};
    int cum = 0;
    for (int i = 0; i < 10; ++i) {
        ca.src[i] = srcs[i]; ca.dst[i] = dsts[i]; ca.n[i] = ns[i];
        ca.cum[i] = cum;
        cum += (ns[i] + 2047) / 2048;
    }
    to_bf16_fused<<<cum, 256, 0, stream>>>(ca, disc);

    gemm_qkv<<<77 * 24, 256, 0, stream>>>(ch, cqw, ckw, cvw, cqb, cvb,
                                          ccos, csin, wq, wk, wvt, T_TOTAL);
    attn_kernel<<<dim3(153, 16), 256, 0, stream>>>(wq, wk, wvt, wq);
    gemm_out<<<77 * 8, 256, 0, stream>>>(wq, cow, cob, d_out, T_TOTAL, disc);
}